// Round 4
// baseline (189.555 us; speedup 1.0000x reference)
//
#include <hip/hip_runtime.h>

// MoE: E=8 experts, Linear(1->32)+ReLU+Linear(32->1), softmax(-sq_err over 4
// context points) weighting.
//
// ROUND-4 = MEASUREMENT BUILD of the round-3 kernel.
// Rounds 2 and 3 landed at identical 15.15 us despite structurally different
// inner loops; the dispatch never shows in rocprof top-5 (harness fills at
// ~40 us mask it), so we have no direct counters. This build repeats the
// knot-evaluation loop REPS=32 times with asm-volatile barriers (inputs made
// opaque each rep -> no CSE; accumulators marked live -> no DCE; final values
// bit-identical to a single pass). Purpose:
//   (1) kernel becomes the longest dispatch -> real VALUBusy/Occupancy/dur_us
//   (2) bench_dur = OH + K0 + 32*K_loop, round-3 gave OH+K0+K_loop = 15.15
//       -> solves the overhead-vs-kernel split.

constexpr int E = 8;
constexpr int H = 32;
constexpr int STRIDE = 34;  // float2 per expert row (padded)
constexpr int REPS = 32;    // measurement multiplier for the knot loop

__global__ __launch_bounds__(256) void moe_kernel(
    const float* __restrict__ ctx,   // [B, 8]
    const float* __restrict__ inp,   // [B, 1]
    const float* __restrict__ W1,    // [E, 1, H]
    const float* __restrict__ b1,    // [E, H]
    const float* __restrict__ W2,    // [E, H, 1]
    const float* __restrict__ b2,    // [E, 1]
    float* __restrict__ out,         // [B, 1]
    int B)
{
    __shared__ __align__(16) float2 crs[E * STRIDE];  // 2176 B

    const int t = threadIdx.x;
    {
        // prologue: one thread per (e,h). w2*relu(w1 x + b1) =
        // (0.5 w2 w1) x + (0.5 w2 b1) + (0.5 w2 |w1|) |x + b1/w1|
        const int e = t >> 5;
        const int h = t & 31;
        const float w1  = W1[e * H + h];
        const float b1v = b1[e * H + h];
        const float w2  = W2[e * H + h];
        const float aw  = fabsf(w1);
        const bool tiny = aw < 1e-20f;
        const float c = tiny ? 0.f : 0.5f * w2 * aw;
        const float r = tiny ? 0.f : (-b1v / w1);
        float pa = tiny ? 0.f : 0.5f * w2 * w1;
        float pb = tiny ? (w2 * fmaxf(b1v, 0.f)) : (0.5f * w2 * b1v);

        crs[e * STRIDE + h] = make_float2(c, r);

        #pragma unroll
        for (int m = 1; m < 32; m <<= 1) {
            pa += __shfl_xor(pa, m);
            pb += __shfl_xor(pb, m);
        }
        if (h == 0) {
            const float beta = pb + b2[e];
            crs[e * STRIDE + 32] = make_float2(pa, -16.0f);            // alpha*|x+16|
            crs[e * STRIDE + 33] = make_float2(beta - 16.0f * pa, 0.f); // K
        }
    }
    __syncthreads();

    const int g = blockIdx.x * 256 + t;
    const int b = g >> 3;
    const int e = g & 7;
    if (b >= B) return;

    const float4 c0 = reinterpret_cast<const float4*>(ctx)[b * 2 + 0];
    const float4 c1 = reinterpret_cast<const float4*>(ctx)[b * 2 + 1];
    float x0 = c0.x, x1 = c0.z, x2 = c1.x, x3 = c1.z;
    float x4 = inp[b];

    // preload this expert's table into registers (17x ds_read_b128)
    float4 crq[17];
    const float4* __restrict__ rowp =
        reinterpret_cast<const float4*>(&crs[e * STRIDE]);
    #pragma unroll
    for (int i = 0; i < 17; ++i) crq[i] = rowp[i];

    const float K = crq[16].z;
    float a0, a1, a2, a3, a4;

    #pragma unroll 1
    for (int rep = 0; rep < REPS; ++rep) {
        // make inputs opaque -> forces full recompute each rep (no CSE)
        asm volatile("" : "+v"(x0), "+v"(x1), "+v"(x2), "+v"(x3), "+v"(x4));
        a0 = K; a1 = K; a2 = K; a3 = K; a4 = K;

        #pragma unroll
        for (int i = 0; i < 16; ++i) {
            {
                const float c = crq[i].x, r = crq[i].y;
                a0 = fmaf(c, fabsf(x0 - r), a0);
                a1 = fmaf(c, fabsf(x1 - r), a1);
                a2 = fmaf(c, fabsf(x2 - r), a2);
                a3 = fmaf(c, fabsf(x3 - r), a3);
                a4 = fmaf(c, fabsf(x4 - r), a4);
            }
            {
                const float c = crq[i].z, r = crq[i].w;
                a0 = fmaf(c, fabsf(x0 - r), a0);
                a1 = fmaf(c, fabsf(x1 - r), a1);
                a2 = fmaf(c, fabsf(x2 - r), a2);
                a3 = fmaf(c, fabsf(x3 - r), a3);
                a4 = fmaf(c, fabsf(x4 - r), a4);
            }
        }
        {   // entry 32: alpha * |x + 16|
            const float c = crq[16].x, r = crq[16].y;
            a0 = fmaf(c, fabsf(x0 - r), a0);
            a1 = fmaf(c, fabsf(x1 - r), a1);
            a2 = fmaf(c, fabsf(x2 - r), a2);
            a3 = fmaf(c, fabsf(x3 - r), a3);
            a4 = fmaf(c, fabsf(x4 - r), a4);
        }
        // mark results live -> earlier reps are not dead code
        asm volatile("" : "+v"(a0), "+v"(a1), "+v"(a2), "+v"(a3), "+v"(a4));
    }

    const float p0 = a0 - c0.y;
    const float p1 = a1 - c0.w;
    const float p2 = a2 - c1.y;
    const float p3 = a3 - c1.w;
    const float err = fmaf(p0, p0, fmaf(p1, p1, fmaf(p2, p2, p3 * p3)));
    const float oe  = a4;

    // softmax(-err) over the 8 experts in this 8-lane group
    float m = err;
    m = fminf(m, __shfl_xor(m, 1));
    m = fminf(m, __shfl_xor(m, 2));
    m = fminf(m, __shfl_xor(m, 4));
    const float w = __expf(m - err);
    float s  = w;
    float wo = w * oe;
    s  += __shfl_xor(s, 1);  wo += __shfl_xor(wo, 1);
    s  += __shfl_xor(s, 2);  wo += __shfl_xor(wo, 2);
    s  += __shfl_xor(s, 4);  wo += __shfl_xor(wo, 4);

    if (e == 0) out[b] = wo / s;
}

extern "C" void kernel_launch(void* const* d_in, const int* in_sizes, int n_in,
                              void* d_out, int out_size, void* d_ws, size_t ws_size,
                              hipStream_t stream) {
    const float* ctx = (const float*)d_in[0];
    const float* inp = (const float*)d_in[1];
    const float* W1  = (const float*)d_in[2];
    const float* b1  = (const float*)d_in[3];
    const float* W2  = (const float*)d_in[4];
    const float* b2  = (const float*)d_in[5];
    float* out = (float*)d_out;

    const int B = in_sizes[1];  // input is [B,1]
    const long long total = (long long)B * 8;
    const int threads = 256;
    const int blocks = (int)((total + threads - 1) / threads);
    hipLaunchKernelGGL(moe_kernel, dim3(blocks), dim3(threads), 0, stream,
                       ctx, inp, W1, b1, W2, b2, out, B);
}

// Round 5
// 15.741 us; speedup vs baseline: 12.0423x; 12.0423x over previous
//
#include <hip/hip_runtime.h>

// MoE: E=8 experts, Linear(1->32)+ReLU+Linear(32->1), softmax(-sq_err over 4
// context points) weighting.
//
// Round-5 design (vs round 3):
//  - measured decomposition (round 4): knot loop = 5.63 us (79% of its
//    4.47 us issue floor), fixed part = 9.52 us. This round attacks the
//    fixed part only; the loop math is unchanged.
//  - grid-stride: 1024 blocks x 4 iterations instead of 4096 blocks.
//    4x fewer WG dispatches, 4x fewer prologues, knot table loaded into
//    registers ONCE per thread (e is iteration-invariant: stride % 8 == 0).
//  - software prefetch: next iteration's context is issued before the
//    330-inst VALU stretch -> L2 latency hides under compute.

constexpr int E = 8;
constexpr int H = 32;
constexpr int STRIDE = 34;  // float2 per expert row (padded)

__global__ __launch_bounds__(256) void moe_kernel(
    const float* __restrict__ ctx,   // [B, 8]
    const float* __restrict__ inp,   // [B, 1]
    const float* __restrict__ W1,    // [E, 1, H]
    const float* __restrict__ b1,    // [E, H]
    const float* __restrict__ W2,    // [E, H, 1]
    const float* __restrict__ b2,    // [E, 1]
    float* __restrict__ out,         // [B, 1]
    int B)
{
    __shared__ __align__(16) float2 crs[E * STRIDE];  // 2176 B

    const int t = threadIdx.x;
    {
        // prologue: one thread per (e,h). w2*relu(w1 x + b1) =
        // (0.5 w2 w1) x + (0.5 w2 b1) + (0.5 w2 |w1|) |x + b1/w1|
        const int e = t >> 5;
        const int h = t & 31;
        const float w1  = W1[e * H + h];
        const float b1v = b1[e * H + h];
        const float w2  = W2[e * H + h];
        const float aw  = fabsf(w1);
        const bool tiny = aw < 1e-20f;
        const float c = tiny ? 0.f : 0.5f * w2 * aw;
        const float r = tiny ? 0.f : (-b1v / w1);
        float pa = tiny ? 0.f : 0.5f * w2 * w1;
        float pb = tiny ? (w2 * fmaxf(b1v, 0.f)) : (0.5f * w2 * b1v);

        crs[e * STRIDE + h] = make_float2(c, r);

        #pragma unroll
        for (int m = 1; m < 32; m <<= 1) {
            pa += __shfl_xor(pa, m);
            pb += __shfl_xor(pb, m);
        }
        if (h == 0) {
            const float beta = pb + b2[e];
            crs[e * STRIDE + 32] = make_float2(pa, -16.0f);             // alpha*|x+16|
            crs[e * STRIDE + 33] = make_float2(beta - 16.0f * pa, 0.f); // K
        }
    }
    __syncthreads();

    const int total  = B * 8;
    const int stride = (int)gridDim.x * 256;   // % 8 == 0 -> e invariant
    int g = (int)blockIdx.x * 256 + t;
    if (g >= total) return;
    const int e = g & 7;

    // expert table -> registers, once per thread (17x ds_read_b128)
    float4 crq[17];
    const float4* __restrict__ rowp =
        reinterpret_cast<const float4*>(&crs[e * STRIDE]);
    #pragma unroll
    for (int i = 0; i < 17; ++i) crq[i] = rowp[i];
    const float K = crq[16].z;

    const float4* __restrict__ ctxq = reinterpret_cast<const float4*>(ctx);

    int b = g >> 3;
    float4 c0 = ctxq[b * 2 + 0];
    float4 c1 = ctxq[b * 2 + 1];
    float x4 = inp[b];

    while (true) {
        // ---- prefetch next iteration's context before the VALU stretch ----
        const int gn = g + stride;
        const bool more = gn < total;
        float4 n0, n1; float n4;
        if (more) {
            const int bn = gn >> 3;
            n0 = ctxq[bn * 2 + 0];
            n1 = ctxq[bn * 2 + 1];
            n4 = inp[bn];
        }

        // ---- 33-knot evaluation at 5 points (pure VALU, register table) ----
        float a0 = K, a1 = K, a2 = K, a3 = K, a4 = K;
        #pragma unroll
        for (int i = 0; i < 16; ++i) {
            {
                const float c = crq[i].x, r = crq[i].y;
                a0 = fmaf(c, fabsf(c0.x - r), a0);
                a1 = fmaf(c, fabsf(c0.z - r), a1);
                a2 = fmaf(c, fabsf(c1.x - r), a2);
                a3 = fmaf(c, fabsf(c1.z - r), a3);
                a4 = fmaf(c, fabsf(x4  - r), a4);
            }
            {
                const float c = crq[i].z, r = crq[i].w;
                a0 = fmaf(c, fabsf(c0.x - r), a0);
                a1 = fmaf(c, fabsf(c0.z - r), a1);
                a2 = fmaf(c, fabsf(c1.x - r), a2);
                a3 = fmaf(c, fabsf(c1.z - r), a3);
                a4 = fmaf(c, fabsf(x4  - r), a4);
            }
        }
        {   // entry 32: alpha * |x + 16|
            const float c = crq[16].x, r = crq[16].y;
            a0 = fmaf(c, fabsf(c0.x - r), a0);
            a1 = fmaf(c, fabsf(c0.z - r), a1);
            a2 = fmaf(c, fabsf(c1.x - r), a2);
            a3 = fmaf(c, fabsf(c1.z - r), a3);
            a4 = fmaf(c, fabsf(x4  - r), a4);
        }

        const float p0 = a0 - c0.y;
        const float p1 = a1 - c0.w;
        const float p2 = a2 - c1.y;
        const float p3 = a3 - c1.w;
        const float err = fmaf(p0, p0, fmaf(p1, p1, fmaf(p2, p2, p3 * p3)));
        const float oe  = a4;

        // softmax(-err) over the 8 experts in this 8-lane group
        float m = err;
        m = fminf(m, __shfl_xor(m, 1));
        m = fminf(m, __shfl_xor(m, 2));
        m = fminf(m, __shfl_xor(m, 4));
        const float w = __expf(m - err);
        float s  = w;
        float wo = w * oe;
        s  += __shfl_xor(s, 1);  wo += __shfl_xor(wo, 1);
        s  += __shfl_xor(s, 2);  wo += __shfl_xor(wo, 2);
        s  += __shfl_xor(s, 4);  wo += __shfl_xor(wo, 4);

        if (e == 0) out[g >> 3] = wo / s;

        if (!more) break;
        g = gn;
        c0 = n0; c1 = n1; x4 = n4;
    }
}

extern "C" void kernel_launch(void* const* d_in, const int* in_sizes, int n_in,
                              void* d_out, int out_size, void* d_ws, size_t ws_size,
                              hipStream_t stream) {
    const float* ctx = (const float*)d_in[0];
    const float* inp = (const float*)d_in[1];
    const float* W1  = (const float*)d_in[2];
    const float* b1  = (const float*)d_in[3];
    const float* W2  = (const float*)d_in[4];
    const float* b2  = (const float*)d_in[5];
    float* out = (float*)d_out;

    const int B = in_sizes[1];  // input is [B,1]
    const long long total = (long long)B * 8;
    int blocks = (int)((total + 255) / 256);
    if (blocks > 1024) blocks = 1024;
    hipLaunchKernelGGL(moe_kernel, dim3(blocks), dim3(256), 0, stream,
                       ctx, inp, W1, b1, W2, b2, out, B);
}